// Round 1
// baseline (260.176 us; speedup 1.0000x reference)
//
#include <hip/hip_runtime.h>

// SequentialEdge: B=256 graphs, R=256 residues/graph, A=8 atoms/residue, D=2.
// Output (int32): 5 chunks (i=-2..2), chunk i has B*(R-|i|)*A*A rows of
// [node_in, node_out, i+D]; rows are -1 where chain_id differs; trailing
// scalar (2D+1)=5 at int index 62,619,648.
//
// Mapping: one WAVE per residue segment (chunk z, graph g, local slot rv).
// All 64 edges of a segment share res_in/res_out/same/rel, and the segment's
// 192-int output block is 16B-aligned (every chunk start is divisible by
// 192 ints). So: 1 wave-uniform chain compare, then lanes 0..47 each emit one
// int4 from shifts/masks only — no divisions by chunk sizes, no double
// decode, perfectly coalesced 16B nontemporal stores.
//
// Chunk table (int4 units, 48 int4 per segment):
//   z=0 (i=-2): Rv=254 lo=2 base4=0
//   z=1 (i=-1): Rv=255 lo=1 base4=3,121,152
//   z=2 (i= 0): Rv=256 lo=0 base4=6,254,592
//   z=3 (i=+1): Rv=255 lo=0 base4=9,400,320
//   z=4 (i=+2): Rv=254 lo=0 base4=12,533,760   (total 15,654,912 int4)

#define INT_TOTAL 62619648u

typedef int iv4 __attribute__((ext_vector_type(4)));

__global__ __launch_bounds__(256)
void seqedge_kernel(const int* __restrict__ chain, int* __restrict__ out) {
    const int z     = (int)blockIdx.z;     // relation id 0..4, offset i = z-2
    const int ioff  = z - 2;
    const int absio = ioff < 0 ? -ioff : ioff;
    const int Rv    = 256 - absio;
    const int lo    = ioff < 0 ? -ioff : 0;

    static const unsigned base4_tab[5] = {0u, 3121152u, 6254592u, 9400320u, 12533760u};
    const unsigned base4 = base4_tab[z];

    // trailing scalar: num_relation = 2D+1
    if (threadIdx.x == 0u && blockIdx.x == 0u && blockIdx.y == 0u && blockIdx.z == 0u)
        out[INT_TOTAL] = 5;

    const unsigned w  = threadIdx.x >> 6;            // wave id in block: one segment per wave
    const int      rv = (int)(blockIdx.x * 4u + w);  // local residue slot within chunk
    if (rv >= Rv) return;                            // tail waves of short chunks idle

    const int g       = (int)blockIdx.y;
    const int res_in  = g * 256 + lo + rv;           // global residue id (node_in side)
    const int res_out = res_in + ioff;               // partner residue, same graph
    const bool same   = chain[res_in] == chain[res_out];  // wave-uniform

    const unsigned l = threadIdx.x & 63u;
    if (l >= 48u) return;                            // 48 int4 = 192 ints per segment

    const unsigned idx4 = base4 + (unsigned)(g * Rv + rv) * 48u + l;

    iv4 v;
    if (!same) {
        v = (iv4){-1, -1, -1, -1};
    } else {
        // lane l covers ints j0..j0+3 of the segment (j = edge*3 + component)
        const unsigned j0 = l * 4u;
        const unsigned e0 = j0 / 3u;                 // compile-time magic mul
        const unsigned c0 = j0 - e0 * 3u;            // rotation phase, period 3 in l
        const unsigned e1 = e0 + 1u;                 // e0<=62, so e1<=63: in-segment
        const int ri8 = res_in * 8, ro8 = res_out * 8;
        const int x0 = ri8 + (int)(e0 >> 3), y0 = ro8 + (int)(e0 & 7u);
        const int x1 = ri8 + (int)(e1 >> 3), y1 = ro8 + (int)(e1 & 7u);
        const int rel = z;
        if (c0 == 0u)      v = (iv4){x0,  y0,  rel, x1 };
        else if (c0 == 1u) v = (iv4){y0,  rel, x1,  y1 };
        else               v = (iv4){rel, x1,  y1,  rel};   // z0==z1==rel
    }
    // output is written once and never re-read by us: skip cache allocation
    __builtin_nontemporal_store(v, reinterpret_cast<iv4*>(out) + idx4);
}

extern "C" void kernel_launch(void* const* d_in, const int* in_sizes, int n_in,
                              void* d_out, int out_size, void* d_ws, size_t ws_size,
                              hipStream_t stream) {
    const int* chain_id = (const int*)d_in[0];
    int* out = (int*)d_out;
    // x: 64 blocks x 4 waves = 256 residue slots (covers Rv<=256)
    // y: graph, z: chunk
    dim3 grid(64, 256, 5);
    seqedge_kernel<<<grid, 256, 0, stream>>>(chain_id, out);
}

// Round 2
// 252.127 us; speedup vs baseline: 1.0319x; 1.0319x over previous
//
#include <hip/hip_runtime.h>

// SequentialEdge: B=256 graphs, R=256 residues/graph, A=8 atoms/residue, D=2.
// Output (int32): 5 chunks (i=-2..2), chunk i has B*(R-|i|)*A*A rows of
// [node_in, node_out, i+D]; rows are -1 where chain_id differs; trailing
// scalar (2D+1)=5 at int index 62,619,648.
//
// Mapping: one WAVE per 8 residue segments (chunk z, graph g, slots rv0..rv0+7).
// All 64 edges of a segment share res_in/res_out/same/rel; each segment's
// 192-int block is 16B-aligned. Lanes 0..47 each emit one int4 per segment.
// Per wave: issue all 16 chain loads, then 8 independent 48-lane dwordx4
// stores -> 8 outstanding stores/wave (round-1 version had 1 store/thread and
// capped at ~2.5 TB/s; the 6.2 TB/s fill kernel loops per thread).
//
// Chunk table (int4 units, 48 int4 per segment):
//   z=0 (i=-2): Rv=254 lo=2 base4=0
//   z=1 (i=-1): Rv=255 lo=1 base4=3,121,152
//   z=2 (i= 0): Rv=256 lo=0 base4=6,254,592
//   z=3 (i=+1): Rv=255 lo=0 base4=9,400,320
//   z=4 (i=+2): Rv=254 lo=0 base4=12,533,760   (total 15,654,912 int4)

#define INT_TOTAL 62619648u
#define NSEG 8

typedef int iv4 __attribute__((ext_vector_type(4)));

__global__ __launch_bounds__(256)
void seqedge_kernel(const int* __restrict__ chain, int* __restrict__ out) {
    const int z     = (int)blockIdx.z;     // relation id 0..4, offset i = z-2
    const int ioff  = z - 2;
    const int absio = ioff < 0 ? -ioff : ioff;
    const int Rv    = 256 - absio;
    const int lo    = ioff < 0 ? -ioff : 0;

    static const unsigned base4_tab[5] = {0u, 3121152u, 6254592u, 9400320u, 12533760u};
    const unsigned base4 = base4_tab[z];

    // trailing scalar: num_relation = 2D+1
    if (threadIdx.x == 0u && blockIdx.x == 0u && blockIdx.y == 0u && blockIdx.z == 0u)
        out[INT_TOTAL] = 5;

    const unsigned l = threadIdx.x & 63u;
    if (l >= 48u) return;                            // 48 int4 = 192 ints per segment

    const unsigned w   = threadIdx.x >> 6;           // wave id in block
    const int      rv0 = (int)((blockIdx.x * 4u + w) * NSEG);  // first residue slot
    const int      g   = (int)blockIdx.y;

    // Phase 1: all chain loads up front (wave-uniform values, L1/L2-broadcast).
    bool same[NSEG];
    int  resin[NSEG];
    #pragma unroll
    for (int s = 0; s < NSEG; ++s) {
        const int rv = rv0 + s;
        resin[s] = g * 256 + lo + rv;
        same[s]  = (rv < Rv) && (chain[resin[s]] == chain[resin[s] + ioff]);
    }

    // Per-lane constants: lane l covers ints j0..j0+3 (j = edge*3 + component)
    const unsigned j0 = l * 4u;
    const unsigned e0 = j0 / 3u;                     // magic mul, e0 <= 62
    const unsigned c0 = j0 - e0 * 3u;                // rotation phase
    const unsigned e1 = e0 + 1u;                     // <= 63: stays in-segment
    const int ai0 = (int)(e0 >> 3), ao0 = (int)(e0 & 7u);
    const int ai1 = (int)(e1 >> 3), ao1 = (int)(e1 & 7u);
    const int rel = z;

    // Phase 2: 8 independent coalesced stores.
    unsigned idx4 = base4 + (unsigned)(g * Rv + rv0) * 48u + l;
    #pragma unroll
    for (int s = 0; s < NSEG; ++s, idx4 += 48u) {
        const int rv = rv0 + s;
        if (rv >= Rv) break;                         // tail of short chunks
        iv4 v;
        if (!same[s]) {
            v = (iv4){-1, -1, -1, -1};
        } else {
            const int ri8 = resin[s] * 8, ro8 = (resin[s] + ioff) * 8;
            const int x0 = ri8 + ai0, y0 = ro8 + ao0;
            const int x1 = ri8 + ai1, y1 = ro8 + ao1;
            if (c0 == 0u)      v = (iv4){x0,  y0,  rel, x1 };
            else if (c0 == 1u) v = (iv4){y0,  rel, x1,  y1 };
            else               v = (iv4){rel, x1,  y1,  rel};
        }
        reinterpret_cast<iv4*>(out)[idx4] = v;
    }
}

extern "C" void kernel_launch(void* const* d_in, const int* in_sizes, int n_in,
                              void* d_out, int out_size, void* d_ws, size_t ws_size,
                              hipStream_t stream) {
    const int* chain_id = (const int*)d_in[0];
    int* out = (int*)d_out;
    // x: 8 blocks x 4 waves x NSEG=8 segments = 256 residue slots (covers Rv<=256)
    // y: graph, z: chunk
    dim3 grid(8, 256, 5);
    seqedge_kernel<<<grid, 256, 0, stream>>>(chain_id, out);
}